// Round 4
// baseline (389.474 us; speedup 1.0000x reference)
//
#include <hip/hip_runtime.h>
#include <math.h>

#define B_    128
#define L_    64
#define C_    300
#define NH_   300
#define K_    20
#define HID_  150
#define N_    (B_*L_)       // 8192
#define N2_   (2*N_)        // 16384
#define NFEAT_ 44427
#define FSTRIDE_ 44428      // padded row stride (16B-aligned rows for float4 loads)
#define ZB_   256           // split-K blocks for mlp1 (1 per CU)
#define KST_  1389          // ceil(NFEAT/32) k-steps
#define KCB_  6             // ceil(KST/ZB) k-steps per block
#define CP_   320           // padded C for bf16 GEMM (mult of 32)
#define NROWS_ 16448        // 257*64: N2_ + pad rows (staging window reads up to +81)

typedef __attribute__((ext_vector_type(8))) short bf16x8;
typedef __attribute__((ext_vector_type(4))) float f32x4;

__device__ __forceinline__ float fast_tanh(float x){
    float e = __expf(2.0f*x);
    return 1.0f - 2.0f/(e + 1.0f);
}

__device__ __forceinline__ unsigned short f2bf(float x){
    union { float f; unsigned u; } a; a.f = x;
    unsigned r = a.u + 0x7FFFu + ((a.u >> 16) & 1u);   // RNE
    return (unsigned short)(r >> 16);
}

__device__ __forceinline__ float bf2f(unsigned short h){
    union { unsigned u; float f; } a; a.u = ((unsigned)h) << 16;
    return a.f;
}

// async global->LDS DMA, 16B/lane; lds dest must be wave-uniform base (+lane*16)
__device__ __forceinline__ void gld16(const void* g, void* l){
    __builtin_amdgcn_global_load_lds(
        (__attribute__((address_space(1))) void*)(g),
        (__attribute__((address_space(3))) void*)(l),
        16, 0, 0);
}

// ---------------------------------------------------------------- embedding
// S[c, s*N + b*64 + l] = emb[tok(s,b,l), c]   (fp32, for pdim/inf kernels)
// grid (64, 5): y-dim splits the 300 channels into 60-chunks (occupancy: 5x waves),
// float4 row reads (4x fewer load instrs; per-thread row stream stays L1-resident).
__global__ void k_embed(const int* __restrict__ sa, const int* __restrict__ sb,
                        const float* __restrict__ emb, float* __restrict__ S){
    int n = blockIdx.x*256 + threadIdx.x;      // 0..16383
    int s = n >> 13;
    int nl = n & (N_-1);
    int tok = s ? sb[nl] : sa[nl];
    const float* row = emb + (long)tok * C_;
    int c0 = blockIdx.y * 60;
    const float4* r4 = (const float4*)(row + c0);   // 1200B rows + 240B chunks: 16B aligned
    #pragma unroll
    for (int i = 0; i < 15; ++i){
        float4 f = r4[i];
        long c = c0 + i*4;
        S[c*N2_ + n]     = f.x;
        S[(c+1)*N2_ + n] = f.y;
        S[(c+2)*N2_ + n] = f.z;
        S[(c+3)*N2_ + n] = f.w;
    }
}

// ------------------------------------------------- transposed bf16 S: SbfT[n][c]
__global__ void k_embedT(const int* __restrict__ sa, const int* __restrict__ sb,
                         const float* __restrict__ emb, unsigned short* __restrict__ sbfT){
    int w = threadIdx.x >> 6, lane = threadIdx.x & 63;
    for (int i = 0; i < 16; ++i){
        long n = (long)blockIdx.x*64 + w*16 + i;
        if (n >= NROWS_) return;
        bool pad = (n >= N2_);
        int tok = 0;
        if (!pad) tok = (n >= N_) ? sb[n - N_] : sa[n];
        const float4* er = (const float4*)(emb + (long)tok * C_);
        #pragma unroll
        for (int p = 0; p < 2; ++p){
            int c4 = p*64 + lane;            // float4 index, c = 4*c4
            if (c4 >= CP_/4) continue;
            ushort4 v = {0,0,0,0};
            if (!pad && c4 < 75){
                float4 f = er[c4];
                v.x = f2bf(f.x); v.y = f2bf(f.y); v.z = f2bf(f.z); v.w = f2bf(f.w);
            }
            ((ushort4*)(sbfT + n*CP_))[c4] = v;
        }
    }
}

// ------------------------------------------------- bf16 conv weights, [plane][o][c]
__global__ void k_wprep(const float* __restrict__ hw1, const float* __restrict__ hw2,
                        const float* __restrict__ hw3, unsigned short* __restrict__ wbf){
    int idx = blockIdx.x*256 + threadIdx.x;    // < 6*320*320 = 614400
    int p = idx / (CP_*CP_), r = idx % (CP_*CP_);
    int o = r / CP_, c = r % CP_;
    int WS, j; const float* hw;
    if (p == 0){ WS = 1; j = 0; hw = hw1; }
    else if (p < 3){ WS = 2; j = p - 1; hw = hw2; }
    else { WS = 3; j = p - 3; hw = hw3; }
    float v = (o < NH_ && c < C_) ? hw[((long)o*C_ + c)*WS + j] : 0.0f;
    wbf[idx] = f2bf(v);
}

// ------------------------------------------------- holistic conv via MFMA v6 (fused)
// All three widths in ONE launch: bid%3 -> WS (consecutive blocks mix WS so each CU
// holds a blend of long/short blocks). 1536 blocks -> 4 resident/CU (LDS-capped,
// 40.4KB) vs v5's 512-block launches (2/CU, latency-starved at the per-chunk
// vmcnt(0)+barrier drain: MfmaUtil 8%, VALU 16%, HBM 3%).
// Tap-major K-loop: chunk ch -> (j = ch/10, kc = ch%10); A row-shift (+j) baked
// into the staging address; BLB holds one 32k x 160n weight slab per chunk.
// 15 gld16/chunk over 4 waves; double-buffered; 10 MFMA/chunk/wave.
__global__ __launch_bounds__(256) void k_hconv6(const unsigned short* __restrict__ sbfT,
        const unsigned short* __restrict__ wbf,
        const float* __restrict__ hb1, const float* __restrict__ hb2,
        const float* __restrict__ hb3, float* __restrict__ apool){
    __shared__ __align__(16) unsigned short ALB[2][320*8];      // 5120 B per buf
    __shared__ __align__(16) unsigned short BLB[2][640*8];      // 10240 B per buf
    __shared__ float P[5][160][3];
    int bid = blockIdx.x;                      // 0..1535
    int wsi = bid % 3;  int rr0 = bid / 3;     // WS = wsi+1
    int nhalf = rr0 & 1; int sbx = rr0 >> 1;   // sbx 0..255
    const int WS = wsi + 1;
    const int Lo = 65 - WS;
    const int NC = 10*WS;                      // k-chunks (j-major, kc-minor)
    const long pofs = (long)((WS*(WS-1))/2) * (CP_*CP_);  // plane base {0,1,3}
    const float* hb = (WS == 1) ? hb1 : (WS == 2) ? hb2 : hb3;

    int tid = threadIdx.x;
    int w = tid >> 6, lane = tid & 63, col = lane & 15, quad = lane >> 4;
    int s = sbx >> 7, b = sbx & 127;
    long row0 = (long)sbx*64;
    int mt0 = (w>>1)*2;
    int olocb = (w&1)*80 + col;
    int nbase = nhalf*160;
    f32x4 acc[2][5] = {};

    auto stage = [&](int ch, int bi){
        int j = ch/10, kc = ch - 10*j;
        int kbase = kc*32;
        #pragma unroll
        for (int q = 0; q < 15; ++q){
            if ((q & 3) != w) continue;        // wave-uniform branch
            int e = q*64 + lane;
            if (q < 5){
                int qc = e/80, rw = e - qc*80;
                gld16(sbfT + (row0 + j + rw)*CP_ + kbase + qc*8, &ALB[bi][q*64*8]);
            } else {
                int eb = e - 320;
                int qc = eb/160, o = eb - qc*160;
                gld16(wbf + pofs + (long)j*(CP_*CP_) + (long)(nbase+o)*CP_ + kbase + qc*8,
                      &BLB[bi][(q-5)*64*8]);
            }
        }
    };

    stage(0, 0);
    for (int ch = 0; ch < NC; ++ch){
        int cur = ch & 1;
        __syncthreads();                       // drains chunk ch's loads; prior reads done
        if (ch+1 < NC) stage(ch+1, cur^1);
        bf16x8 a0 = *(const bf16x8*)&ALB[cur][(quad*80 + mt0*16 + col)*8];
        bf16x8 a1 = *(const bf16x8*)&ALB[cur][(quad*80 + (mt0+1)*16 + col)*8];
        #pragma unroll
        for (int ni = 0; ni < 5; ++ni){
            bf16x8 bfr = *(const bf16x8*)&BLB[cur][(quad*160 + olocb + ni*16)*8];
            acc[0][ni] = __builtin_amdgcn_mfma_f32_16x16x32_bf16(a0, bfr, acc[0][ni], 0,0,0);
            acc[1][ni] = __builtin_amdgcn_mfma_f32_16x16x32_bf16(a1, bfr, acc[1][ni], 0,0,0);
        }
    }

    float rmax[5], rmin[5], rsum[5];
    #pragma unroll
    for (int ni = 0; ni < 5; ++ni){
        int oloc = olocb + ni*16;
        int o = nbase + oloc;
        float bias = (o < NH_) ? hb[o] : 0.0f;
        float vmax = -1e30f, vmin = 1e30f, vsum = 0.0f;
        #pragma unroll
        for (int mi = 0; mi < 2; ++mi){
            int mt = mt0 + mi;
            #pragma unroll
            for (int r = 0; r < 4; ++r){
                int t = mt*16 + quad*4 + r;
                if (t < Lo){
                    float z = acc[mi][ni][r] + bias;
                    vmax = fmaxf(vmax, z); vmin = fminf(vmin, z);
                    vsum += fast_tanh(z);
                }
            }
        }
        for (int m = 16; m < 64; m <<= 1){
            vmax = fmaxf(vmax, __shfl_xor(vmax, m, 64));
            vmin = fminf(vmin, __shfl_xor(vmin, m, 64));
            vsum += __shfl_xor(vsum, m, 64);
        }
        rmax[ni] = vmax; rmin[ni] = vmin; rsum[ni] = vsum;
        if (w < 2 && quad == 0){
            P[ni][oloc][0] = vmax; P[ni][oloc][1] = vmin; P[ni][oloc][2] = vsum;
        }
    }
    __syncthreads();
    if (w >= 2 && quad == 0){
        #pragma unroll
        for (int ni = 0; ni < 5; ++ni){
            int oloc = olocb + ni*16;
            int o = nbase + oloc;
            if (o < NH_){
                float vmax = fmaxf(rmax[ni], P[ni][oloc][0]);
                float vmin = fminf(rmin[ni], P[ni][oloc][1]);
                float vsum = rsum[ni] + P[ni][oloc][2];
                long base = ((long)((s*3 + (WS-1))*3)) * (long)(B_*NH_) + (long)b*NH_ + o;
                apool[base]                  = fast_tanh(vmax);
                apool[base + (long)(B_*NH_)] = -fast_tanh(vmin);
                apool[base + 2L*(B_*NH_)]    = vsum / (float)Lo;
            }
        }
    }
}

// ------------------------------------------------- per-dim conv + pooling v2
__global__ __launch_bounds__(256) void k_pdim(const float* __restrict__ S,
    const float* __restrict__ pw1, const float* __restrict__ pb1,
    const float* __restrict__ pw2, const float* __restrict__ pb2,
    const float* __restrict__ pw3, const float* __restrict__ pb3,
    float* __restrict__ ppool){
    long tid = (long)blockIdx.x*256 + threadIdx.x;   // < 1,536,000
    int k = (int)(tid % 20);
    long r = tid / 20;
    int c = (int)(r % 300); r /= 300;
    int b = (int)(r % 128); int s = (int)(r / 128);
    const float* row = S + (long)c*N2_ + (long)s*N_ + b*64;
    int ck = c*20 + k;
    float w10 = pw1[ck];
    float w20 = pw2[ck*2], w21 = pw2[ck*2+1];
    float w30 = pw3[ck*3], w31 = pw3[ck*3+1], w32 = pw3[ck*3+2];
    float bb1 = pb1[ck], bb2 = pb2[ck], bb3 = pb3[ck];

    float x[64];
    const float4* rp = (const float4*)row;
    #pragma unroll
    for (int i = 0; i < 16; ++i){
        float4 v = rp[i];
        x[i*4+0]=v.x; x[i*4+1]=v.y; x[i*4+2]=v.z; x[i*4+3]=v.w;
    }

    float mx1=-1e30f, mn1=1e30f, mx2=-1e30f, mn2=1e30f, mx3=-1e30f, mn3=1e30f;
    #pragma unroll
    for (int t = 0; t < 64; ++t){
        float z1 = fmaf(w10, x[t], bb1);
        mx1 = fmaxf(mx1, z1); mn1 = fminf(mn1, z1);
    }
    #pragma unroll
    for (int t = 0; t < 63; ++t){
        float z2 = fmaf(w21, x[t+1], fmaf(w20, x[t], bb2));
        mx2 = fmaxf(mx2, z2); mn2 = fminf(mn2, z2);
    }
    #pragma unroll
    for (int t = 0; t < 62; ++t){
        float z3 = fmaf(w32, x[t+2], fmaf(w31, x[t+1], fmaf(w30, x[t], bb3)));
        mx3 = fmaxf(mx3, z3); mn3 = fminf(mn3, z3);
    }

    float outs[6] = { fast_tanh(mx1), -fast_tanh(mn1),
                      fast_tanh(mx2), -fast_tanh(mn2),
                      fast_tanh(mx3), -fast_tanh(mn3) };
    long stride_sw = 128L*6000L;
    long off = (long)b*6000 + (long)c*20 + k;
    #pragma unroll
    for (int wsi = 0; wsi < 3; ++wsi)
        #pragma unroll
        for (int pool = 0; pool < 2; ++pool){
            long slot = (long)((s*3+wsi)*2 + pool);
            ppool[slot*stride_sw + off] = outs[wsi*2+pool];
        }
}

// ------------------------------------------------- whole-sentence (inf) pools
__global__ void k_inf(const float* __restrict__ S, float* __restrict__ ainf){
    int sbx = blockIdx.x; int s = sbx >> 7, b = sbx & 127;
    int tid = threadIdx.x;
    long base = (long)s*N_ + b*64;
    float vmax = -1e30f, vnmax = -1e30f, vsum = 0.f;
    for (int idx = tid; idx < C_*64; idx += 256){
        int c = idx >> 6, l = idx & 63;
        float v = S[(long)c*N2_ + base + l];
        vmax = fmaxf(vmax, v);
        vnmax = fmaxf(vnmax, -v);
        vsum += v;
    }
    for (int m = 1; m < 64; m <<= 1){
        vmax  = fmaxf(vmax,  __shfl_xor(vmax, m, 64));
        vnmax = fmaxf(vnmax, __shfl_xor(vnmax, m, 64));
        vsum += __shfl_xor(vsum, m, 64);
    }
    __shared__ float red[3][4];
    int w = tid >> 6;
    if ((tid & 63) == 0){ red[0][w]=vmax; red[1][w]=vnmax; red[2][w]=vsum; }
    __syncthreads();
    if (tid == 0){
        float a = fmaxf(fmaxf(red[0][0],red[0][1]),fmaxf(red[0][2],red[0][3]));
        float nn= fmaxf(fmaxf(red[1][0],red[1][1]),fmaxf(red[1][2],red[1][3]));
        float su= red[2][0]+red[2][1]+red[2][2]+red[2][3];
        ainf[(s*3+0)*128 + b] = a;
        ainf[(s*3+1)*128 + b] = nn;
        ainf[(s*3+2)*128 + b] = su / (float)(C_*64);
    }
}

// ------------------------------------------------- finite-ws pair features
__global__ void k_pairs(const float* __restrict__ apool, float* __restrict__ feat){
    int b = blockIdx.x, p = blockIdx.y, q = blockIdx.z;
    int w1 = q / 3, w2 = q % 3;
    int lane = threadIdx.x;
    const float* x1 = apool + ((long)((0*3 + w1)*3 + p))*(long)(B_*NH_) + (long)b*NH_;
    const float* x2 = apool + ((long)((1*3 + w2)*3 + p))*(long)(B_*NH_) + (long)b*NH_;
    float dot=0, n1=0, n2=0, d2=0;
    long fb = (long)b*FSTRIDE_;
    long vbase = 24 + (long)p*2721 + (long)q*302;
    for (int i = lane; i < NH_; i += 64){
        float a = x1[i], bb = x2[i];
        dot = fmaf(a, bb, dot); n1 = fmaf(a, a, n1); n2 = fmaf(bb, bb, n2);
        float dd = a - bb + 1e-6f;
        d2 = fmaf(dd, dd, d2);
        feat[fb + vbase + 2 + i] = fabsf(a - bb);
    }
    for (int m = 1; m < 64; m <<= 1){
        dot += __shfl_xor(dot, m, 64);
        n1  += __shfl_xor(n1, m, 64);
        n2  += __shfl_xor(n2, m, 64);
        d2  += __shfl_xor(d2, m, 64);
    }
    if (lane == 0){
        float cosv = dot / fmaxf(sqrtf(n1)*sqrtf(n2), 1e-8f);
        float distv = sqrtf(d2);
        feat[fb + vbase + 0] = cosv;
        feat[fb + vbase + 1] = distv;
        if (w1 == w2){
            feat[fb + p*8 + w1*2 + 0] = cosv;
            feat[fb + p*8 + w1*2 + 1] = distv;
        }
    }
}

// ------------------------------------------------- inf features (scalar dims)
__global__ void k_infeat(const float* __restrict__ ainf, float* __restrict__ feat){
    int t = threadIdx.x;
    if (t >= 384) return;
    int b = t & 127, p = t >> 7;
    float x1 = ainf[(0*3+p)*128 + b];
    float x2 = ainf[(1*3+p)*128 + b];
    float cosv = (x1*x2) / fmaxf(fabsf(x1)*fabsf(x2), 1e-8f);
    float distv = fabsf(x1 - x2 + 1e-6f);
    long fb = (long)b*FSTRIDE_;
    feat[fb + p*8 + 6] = cosv;
    feat[fb + p*8 + 7] = distv;
    long vb = 24 + (long)p*2721 + 9L*302;
    feat[fb + vb + 0] = cosv;
    feat[fb + vb + 1] = distv;
    feat[fb + vb + 2] = fabsf(x1 - x2);
}

// ------------------------------------------------- per-dim pair features v2
// One 256-thread block per (b, pw). Stage both 6000-float rows coalesced from
// global, transpose to LDS [k][305]. Wave w reduces k = w, w+4, ... — identical
// lane->c map + shuffle order as v1 (bit-identical results).
__global__ __launch_bounds__(256) void k_pdimfeat(const float* __restrict__ ppool,
                                                  float* __restrict__ feat){
    __shared__ float X1[20*305];
    __shared__ float X2[20*305];
    int b = blockIdx.x, pw = blockIdx.y;
    int pool = pw / 3, wsi = pw % 3;
    int tid = threadIdx.x;
    long stride_sw = 128L*6000L;
    const float* x1 = ppool + (long)((0*3+wsi)*2+pool)*stride_sw + (long)b*6000;
    const float* x2 = ppool + (long)((1*3+wsi)*2+pool)*stride_sw + (long)b*6000;
    for (int idx = tid; idx < 6000; idx += 256){
        int c = idx / 20, k = idx - 20*c;      // element (c,k): original x[c*20+k]
        X1[k*305 + c] = x1[idx];
        X2[k*305 + c] = x2[idx];
    }
    __syncthreads();
    int w = tid >> 6, lane = tid & 63;
    for (int k = w; k < 20; k += 4){
        float dot=0, n1=0, n2=0, d2=0;
        long fb = (long)b*FSTRIDE_ + 8187 + (long)pw*6040 + (long)k*302;
        for (int c = lane; c < C_; c += 64){
            float a = X1[k*305 + c], bb = X2[k*305 + c];
            dot = fmaf(a, bb, dot); n1 = fmaf(a, a, n1); n2 = fmaf(bb, bb, n2);
            float dd = a - bb + 1e-6f;
            d2 = fmaf(dd, dd, d2);
            feat[fb + 2 + c] = fabsf(a - bb);
        }
        for (int m = 1; m < 64; m <<= 1){
            dot += __shfl_xor(dot, m, 64);
            n1  += __shfl_xor(n1, m, 64);
            n2  += __shfl_xor(n2, m, 64);
            d2  += __shfl_xor(d2, m, 64);
        }
        if (lane == 0){
            feat[fb + 0] = dot / fmaxf(sqrtf(n1)*sqrtf(n2), 1e-8f);
            feat[fb + 1] = sqrtf(d2);
        }
    }
}

// ------------------------------------------------- MLP layer 1: MFMA split-K v6
// C[128,150] = feat @ W1 via bf16 hi/lo split (3-term: hh + lh + hl), fp32 accum.
// A rows FSTRIDE_-padded (16B aligned) -> 2x float4 loads per step per lane;
// masked scalar path only on the final partial k-step.
__global__ __launch_bounds__(512) void k_mlp1(const float* __restrict__ feat,
        const float* __restrict__ W1, float* __restrict__ hpart){
    __shared__ __align__(16) unsigned short Bh[2][5120];   // 4 k-octets * 160 n * 8
    __shared__ __align__(16) unsigned short Bl[2][5120];
    int tid = threadIdx.x;
    int w = tid >> 6, lane = tid & 63, col = lane & 15, quad = lane >> 4;
    int z = blockIdx.x;
    int t0 = z * KCB_;
    int ns = KST_ - t0; if (ns > KCB_) ns = KCB_;
    long hbase = (long)z * (128*160);
    int mrow = w*16 + col;                       // wave's m-tile row for A-frag

    if (ns <= 0){
        #pragma unroll
        for (int ni = 0; ni < 10; ++ni)
            #pragma unroll
            for (int r = 0; r < 4; ++r)
                hpart[hbase + (long)(w*16 + quad*4 + r)*160 + ni*16 + col] = 0.0f;
        return;
    }

    // B staging assignment: 2560 (k-pair, n) cells, 5 per thread (constant per step)
    int k2a[5], na[5];
    #pragma unroll
    for (int i = 0; i < 5; ++i){
        int p = i*512 + tid;
        k2a[i] = p / 160; na[i] = p - 160*k2a[i];   // k2 in 0..15 (k = 2*k2), n in 0..159
    }

    const float* arow = feat + (long)mrow * FSTRIDE_;
    float af[8];                 // raw A dwords for current/next step
    float bf0[5], bf1[5];        // raw B pair values
    bf16x8 ah, al;               // current A frags
    f32x4 acc[10] = {};

#define LOADA(STEP) do { \
        int ks_ = t0 + (STEP); \
        int kb_ = ks_*32 + quad*8; \
        if (ks_ < 1388){ \
            float4 f0_ = *(const float4*)(arow + kb_); \
            float4 f1_ = *(const float4*)(arow + kb_ + 4); \
            af[0]=f0_.x; af[1]=f0_.y; af[2]=f0_.z; af[3]=f0_.w; \
            af[4]=f1_.x; af[5]=f1_.y; af[6]=f1_.z; af[7]=f1_.w; \
        } else { \
            _Pragma("unroll") \
            for (int j_ = 0; j_ < 8; ++j_){ \
                int k_ = kb_ + j_; \
                af[j_] = (k_ < NFEAT_) ? arow[k_] : 0.0f; \
            } \
        } } while(0)

#define LOADB(STEP) do { \
        int kb_ = (t0 + (STEP))*32; \
        _Pragma("unroll") \
        for (int i_ = 0; i_ < 5; ++i_){ \
            int k_ = kb_ + 2*k2a[i_]; int n_ = na[i_]; \
            bf0[i_] = (k_   < NFEAT_ && n_ < HID_) ? W1[(long)k_*HID_ + n_]     : 0.0f; \
            bf1[i_] = (k_+1 < NFEAT_ && n_ < HID_) ? W1[(long)(k_+1)*HID_ + n_] : 0.0f; \
        } } while(0)

#define CVTA() do { \
        _Pragma("unroll") \
        for (int j_ = 0; j_ < 8; ++j_){ \
            unsigned short h_ = f2bf(af[j_]); \
            unsigned short l_ = f2bf(af[j_] - bf2f(h_)); \
            ah[j_] = (short)h_; al[j_] = (short)l_; \
        } } while(0)

#define WRITEB(BUF) do { \
        _Pragma("unroll") \
        for (int i_ = 0; i_ < 5; ++i_){ \
            int k2_ = k2a[i_]; int n_ = na[i_]; \
            int q_ = k2_ >> 2, off_ = k2_ & 3; \
            unsigned short h0_ = f2bf(bf0[i_]); \
            unsigned short l0_ = f2bf(bf0[i_] - bf2f(h0_)); \
            unsigned short h1_ = f2bf(bf1[i_]); \
            unsigned short l1_ = f2bf(bf1[i_] - bf2f(h1_)); \
            int ui_ = (q_*160 + n_)*4 + off_; \
            ((unsigned*)Bh[BUF])[ui_] = (unsigned)h0_ | ((unsigned)h1_ << 16); \
            ((unsigned*)Bl[BUF])[ui_] = (unsigned)l0_ | ((unsigned)l1_ << 16); \
        } } while(0)

    // prologue: fetch step 0, stage B(0) into buf 0
    LOADB(0);
    LOADA(0);
    WRITEB(0);

    for (int t = 0; t < ns; ++t){
        __syncthreads();                       // B(t) LDS writes visible to all waves
        CVTA();                                // A(t) raw -> frags (waits its vmcnt)
        bool more = (t+1 < ns);
        if (more){ LOADA(t+1); LOADB(t+1); }   // issue next-step global loads early
        int bi = t & 1;
        #pragma unroll
        for (int ni = 0; ni < 10; ++ni){
            bf16x8 bh = *(const bf16x8*)&Bh[bi][(quad*160 + ni*16 + col)*8];
            bf16x8 bl = *(const bf16x8*)&Bl[bi][(quad*160 + ni*16 + col)*8];
            acc[ni] = __builtin_amdgcn_mfma_f32_16x16x32_bf16(ah, bh, acc[ni], 0,0,0);
            acc[ni] = __builtin_amdgcn_mfma_f32_16x16x32_bf16(al, bh, acc[ni], 0,0,0);
            acc[ni] = __builtin_amdgcn_mfma_f32_16x16x32_bf16(ah, bl, acc[ni], 0,0,0);
        }
        if (more) WRITEB((t+1)&1);             // waits B(t+1) vmcnt; other buffer
    }

#undef LOADA
#undef LOADB
#undef CVTA
#undef WRITEB

    #pragma unroll
    for (int ni = 0; ni < 10; ++ni)
        #pragma unroll
        for (int r = 0; r < 4; ++r)
            hpart[hbase + (long)(w*16 + quad*4 + r)*160 + ni*16 + col] = acc[ni][r];
}

// ------------------------------------------------- reduce split-K partials v2
// grid (75, 4): y-chunk sums 64 z's -> 300 blocks. k_final sums the 4 slices.
__global__ void k_red(const float* __restrict__ hpart, float* __restrict__ hpre4){
    int t = blockIdx.x*256 + threadIdx.x;
    if (t >= 128*HID_) return;
    int y = blockIdx.y;
    int b = t / HID_, n = t % HID_;
    float s = 0.0f;
    int z0 = y*64;
    for (int z = z0; z < z0+64; ++z)
        s += hpart[(long)z*(128*160) + (long)b*160 + n];
    hpre4[(long)y*(128*HID_) + t] = s;
}

// ------------------------------------------------- tanh + layer2 + log_softmax
__global__ void k_final(const float* __restrict__ hpre4, const float* __restrict__ b1,
        const float* __restrict__ W2, const float* __restrict__ b2,
        float* __restrict__ out){
    int b = threadIdx.x;
    if (b >= 128) return;
    float z0 = b2[0], z1 = b2[1];
    for (int n = 0; n < HID_; ++n){
        int idx = b*HID_ + n;
        float hp = hpre4[idx] + hpre4[19200 + idx] + hpre4[38400 + idx] + hpre4[57600 + idx];
        float hv = fast_tanh(hp + b1[n]);
        z0 = fmaf(hv, W2[n*2+0], z0);
        z1 = fmaf(hv, W2[n*2+1], z1);
    }
    float m = fmaxf(z0, z1);
    float lse = m + logf(expf(z0-m) + expf(z1-m));
    out[b*2+0] = z0 - lse;
    out[b*2+1] = z1 - lse;
}

extern "C" void kernel_launch(void* const* d_in, const int* in_sizes, int n_in,
                              void* d_out, int out_size, void* d_ws, size_t ws_size,
                              hipStream_t stream){
    const int*   sa  = (const int*)d_in[0];
    const int*   sb  = (const int*)d_in[1];
    const float* emb = (const float*)d_in[2];
    const float* hw1 = (const float*)d_in[3];
    const float* hb1 = (const float*)d_in[4];
    const float* pw1 = (const float*)d_in[5];
    const float* pb1 = (const float*)d_in[6];
    const float* hw2 = (const float*)d_in[7];
    const float* hb2 = (const float*)d_in[8];
    const float* pw2 = (const float*)d_in[9];
    const float* pb2 = (const float*)d_in[10];
    const float* hw3 = (const float*)d_in[11];
    const float* hb3 = (const float*)d_in[12];
    const float* pw3 = (const float*)d_in[13];
    const float* pb3 = (const float*)d_in[14];
    const float* W1  = (const float*)d_in[15];
    const float* b1  = (const float*)d_in[16];
    const float* W2  = (const float*)d_in[17];
    const float* b2  = (const float*)d_in[18];
    float* out = (float*)d_out;

    float* ws    = (float*)d_ws;
    float* S     = ws;                       // 300*16384      = 4,915,200
    float* APOOL = S + 4915200;              // 2*3*3*128*300  =   691,200
    float* AINF  = APOOL + 691200;           // 2*3*128        =       768
    float* PPOOL = AINF + 768;               // 2*3*2*128*6000 = 9,216,000
    float* FEAT  = PPOOL + 9216000;          // 128*44428      = 5,686,784 (padded rows)
    float* HPRE  = FEAT + 5686784;           // 4*128*150      =    76,800
    // time-multiplexed overlays:
    //  - SbfT (16448*320 bf16 = 2,631,680 floats) + Wbf overlay PPOOL until hconv6
    //    finishes (k_pdim then overwrites)
    //  - HPART (256*128*160 = 5,242,880 floats) overlays S..AINF (dead by mlp1)
    unsigned short* SBFT = (unsigned short*)PPOOL;
    unsigned short* WBF  = (unsigned short*)(PPOOL + 2631680);
    float* HPART = ws;

    k_embed<<<dim3(64, 5), 256, 0, stream>>>(sa, sb, emb, S);
    k_embedT<<<257, 256, 0, stream>>>(sa, sb, emb, SBFT);
    k_wprep<<<2400, 256, 0, stream>>>(hw1, hw2, hw3, WBF);
    k_hconv6<<<1536, 256, 0, stream>>>(SBFT, WBF, hb1, hb2, hb3, APOOL);
    k_pdim<<<6000, 256, 0, stream>>>(S, pw1,pb1, pw2,pb2, pw3,pb3, PPOOL);
    k_inf<<<256, 256, 0, stream>>>(S, AINF);
    k_pairs<<<dim3(128,3,9), 64, 0, stream>>>(APOOL, FEAT);
    k_infeat<<<1, 384, 0, stream>>>(AINF, FEAT);
    k_pdimfeat<<<dim3(128, 6), 256, 0, stream>>>(PPOOL, FEAT);
    k_mlp1<<<dim3(ZB_), 512, 0, stream>>>(FEAT, W1, HPART);
    k_red<<<dim3(75, 4), 256, 0, stream>>>(HPART, HPRE);
    k_final<<<1, 128, 0, stream>>>(HPRE, b1, W2, b2, out);
}

// Round 5
// 376.308 us; speedup vs baseline: 1.0350x; 1.0350x over previous
//
#include <hip/hip_runtime.h>
#include <math.h>

#define B_    128
#define L_    64
#define C_    300
#define NH_   300
#define K_    20
#define HID_  150
#define N_    (B_*L_)       // 8192
#define N2_   (2*N_)        // 16384
#define NFEAT_ 44427
#define FSTRIDE_ 44428      // padded row stride (16B-aligned rows for float4 loads)
#define ZB_   256           // split-K blocks for mlp1 (1 per CU)
#define KST_  1389          // ceil(NFEAT/32) k-steps
#define KCB_  6             // ceil(KST/ZB) k-steps per block
#define CP_   320           // padded C for bf16 GEMM (mult of 32)
#define NROWS_ 16448        // 257*64: N2_ + pad rows (staging window reads up to +81)

typedef __attribute__((ext_vector_type(8))) short bf16x8;
typedef __attribute__((ext_vector_type(4))) float f32x4;

__device__ __forceinline__ float fast_tanh(float x){
    float e = __expf(2.0f*x);
    return 1.0f - 2.0f/(e + 1.0f);
}

__device__ __forceinline__ unsigned short f2bf(float x){
    union { float f; unsigned u; } a; a.f = x;
    unsigned r = a.u + 0x7FFFu + ((a.u >> 16) & 1u);   // RNE
    return (unsigned short)(r >> 16);
}

__device__ __forceinline__ float bf2f(unsigned short h){
    union { unsigned u; float f; } a; a.u = ((unsigned)h) << 16;
    return a.f;
}

// async global->LDS DMA, 16B/lane; lds dest must be wave-uniform base (+lane*16)
__device__ __forceinline__ void gld16(const void* g, void* l){
    __builtin_amdgcn_global_load_lds(
        (__attribute__((address_space(1))) void*)(g),
        (__attribute__((address_space(3))) void*)(l),
        16, 0, 0);
}

// ---------------------------------------------------------------- embedding
// S[c, s*N + b*64 + l] = emb[tok(s,b,l), c]   (fp32, for pdim/inf kernels)
// grid (64, 5): y-dim splits the 300 channels into 60-chunks (occupancy: 5x waves),
// float4 row reads (4x fewer load instrs; per-thread row stream stays L1-resident).
__global__ void k_embed(const int* __restrict__ sa, const int* __restrict__ sb,
                        const float* __restrict__ emb, float* __restrict__ S){
    int n = blockIdx.x*256 + threadIdx.x;      // 0..16383
    int s = n >> 13;
    int nl = n & (N_-1);
    int tok = s ? sb[nl] : sa[nl];
    const float* row = emb + (long)tok * C_;
    int c0 = blockIdx.y * 60;
    const float4* r4 = (const float4*)(row + c0);   // 1200B rows + 240B chunks: 16B aligned
    #pragma unroll
    for (int i = 0; i < 15; ++i){
        float4 f = r4[i];
        long c = c0 + i*4;
        S[c*N2_ + n]     = f.x;
        S[(c+1)*N2_ + n] = f.y;
        S[(c+2)*N2_ + n] = f.z;
        S[(c+3)*N2_ + n] = f.w;
    }
}

// ------------------------------------------------- transposed bf16 S: SbfT[n][c]
__global__ void k_embedT(const int* __restrict__ sa, const int* __restrict__ sb,
                         const float* __restrict__ emb, unsigned short* __restrict__ sbfT){
    int w = threadIdx.x >> 6, lane = threadIdx.x & 63;
    for (int i = 0; i < 16; ++i){
        long n = (long)blockIdx.x*64 + w*16 + i;
        if (n >= NROWS_) return;
        bool pad = (n >= N2_);
        int tok = 0;
        if (!pad) tok = (n >= N_) ? sb[n - N_] : sa[n];
        const float4* er = (const float4*)(emb + (long)tok * C_);
        #pragma unroll
        for (int p = 0; p < 2; ++p){
            int c4 = p*64 + lane;            // float4 index, c = 4*c4
            if (c4 >= CP_/4) continue;
            ushort4 v = {0,0,0,0};
            if (!pad && c4 < 75){
                float4 f = er[c4];
                v.x = f2bf(f.x); v.y = f2bf(f.y); v.z = f2bf(f.z); v.w = f2bf(f.w);
            }
            ((ushort4*)(sbfT + n*CP_))[c4] = v;
        }
    }
}

// ------------------------------------------------- bf16 conv weights, [plane][o][c]
__global__ void k_wprep(const float* __restrict__ hw1, const float* __restrict__ hw2,
                        const float* __restrict__ hw3, unsigned short* __restrict__ wbf){
    int idx = blockIdx.x*256 + threadIdx.x;    // < 6*320*320 = 614400
    int p = idx / (CP_*CP_), r = idx % (CP_*CP_);
    int o = r / CP_, c = r % CP_;
    int WS, j; const float* hw;
    if (p == 0){ WS = 1; j = 0; hw = hw1; }
    else if (p < 3){ WS = 2; j = p - 1; hw = hw2; }
    else { WS = 3; j = p - 3; hw = hw3; }
    float v = (o < NH_ && c < C_) ? hw[((long)o*C_ + c)*WS + j] : 0.0f;
    wbf[idx] = f2bf(v);
}

// ------------------------------------------------- holistic conv via MFMA v7
// = v6 (all widths fused, bid%3 -> WS) + XCD-bijective swizzle:
//   launch index i -> work w = (i&7)*192 + (i>>3)  (1536 = 8*192, bijective).
// HW round-robins blockIdx across the 8 XCDs, so XCD x owns works [192x,192x+192):
// 32 contiguous sbx groups x {2 nhalf x 3 WS}. Working set per XCD = 1.3MB SbfT
// + 1.2MB WBF -> L2-resident; the 6-way A-slab re-read and 3x tap re-read become
// L2 hits (v6: 58MB HBM FETCH at 640GB/s = latency-bound on HBM misses).
__global__ __launch_bounds__(256) void k_hconv7(const unsigned short* __restrict__ sbfT,
        const unsigned short* __restrict__ wbf,
        const float* __restrict__ hb1, const float* __restrict__ hb2,
        const float* __restrict__ hb3, float* __restrict__ apool){
    __shared__ __align__(16) unsigned short ALB[2][320*8];      // 5120 B per buf
    __shared__ __align__(16) unsigned short BLB[2][640*8];      // 10240 B per buf
    __shared__ float P[5][160][3];
    int i0 = blockIdx.x;                       // 0..1535
    int bid = (i0 & 7)*192 + (i0 >> 3);        // XCD-contiguous work id
    int wsi = bid % 3;  int rr0 = bid / 3;     // WS = wsi+1
    int nhalf = rr0 & 1; int sbx = rr0 >> 1;   // sbx 0..255
    const int WS = wsi + 1;
    const int Lo = 65 - WS;
    const int NC = 10*WS;                      // k-chunks (j-major, kc-minor)
    const long pofs = (long)((WS*(WS-1))/2) * (CP_*CP_);  // plane base {0,1,3}
    const float* hb = (WS == 1) ? hb1 : (WS == 2) ? hb2 : hb3;

    int tid = threadIdx.x;
    int w = tid >> 6, lane = tid & 63, col = lane & 15, quad = lane >> 4;
    int s = sbx >> 7, b = sbx & 127;
    long row0 = (long)sbx*64;
    int mt0 = (w>>1)*2;
    int olocb = (w&1)*80 + col;
    int nbase = nhalf*160;
    f32x4 acc[2][5] = {};

    auto stage = [&](int ch, int bi){
        int j = ch/10, kc = ch - 10*j;
        int kbase = kc*32;
        #pragma unroll
        for (int q = 0; q < 15; ++q){
            if ((q & 3) != w) continue;        // wave-uniform branch
            int e = q*64 + lane;
            if (q < 5){
                int qc = e/80, rw = e - qc*80;
                gld16(sbfT + (row0 + j + rw)*CP_ + kbase + qc*8, &ALB[bi][q*64*8]);
            } else {
                int eb = e - 320;
                int qc = eb/160, o = eb - qc*160;
                gld16(wbf + pofs + (long)j*(CP_*CP_) + (long)(nbase+o)*CP_ + kbase + qc*8,
                      &BLB[bi][(q-5)*64*8]);
            }
        }
    };

    stage(0, 0);
    for (int ch = 0; ch < NC; ++ch){
        int cur = ch & 1;
        __syncthreads();                       // drains chunk ch's loads; prior reads done
        if (ch+1 < NC) stage(ch+1, cur^1);
        bf16x8 a0 = *(const bf16x8*)&ALB[cur][(quad*80 + mt0*16 + col)*8];
        bf16x8 a1 = *(const bf16x8*)&ALB[cur][(quad*80 + (mt0+1)*16 + col)*8];
        #pragma unroll
        for (int ni = 0; ni < 5; ++ni){
            bf16x8 bfr = *(const bf16x8*)&BLB[cur][(quad*160 + olocb + ni*16)*8];
            acc[0][ni] = __builtin_amdgcn_mfma_f32_16x16x32_bf16(a0, bfr, acc[0][ni], 0,0,0);
            acc[1][ni] = __builtin_amdgcn_mfma_f32_16x16x32_bf16(a1, bfr, acc[1][ni], 0,0,0);
        }
    }

    float rmax[5], rmin[5], rsum[5];
    #pragma unroll
    for (int ni = 0; ni < 5; ++ni){
        int oloc = olocb + ni*16;
        int o = nbase + oloc;
        float bias = (o < NH_) ? hb[o] : 0.0f;
        float vmax = -1e30f, vmin = 1e30f, vsum = 0.0f;
        #pragma unroll
        for (int mi = 0; mi < 2; ++mi){
            int mt = mt0 + mi;
            #pragma unroll
            for (int r = 0; r < 4; ++r){
                int t = mt*16 + quad*4 + r;
                if (t < Lo){
                    float z = acc[mi][ni][r] + bias;
                    vmax = fmaxf(vmax, z); vmin = fminf(vmin, z);
                    vsum += fast_tanh(z);
                }
            }
        }
        for (int m = 16; m < 64; m <<= 1){
            vmax = fmaxf(vmax, __shfl_xor(vmax, m, 64));
            vmin = fminf(vmin, __shfl_xor(vmin, m, 64));
            vsum += __shfl_xor(vsum, m, 64);
        }
        rmax[ni] = vmax; rmin[ni] = vmin; rsum[ni] = vsum;
        if (w < 2 && quad == 0){
            P[ni][oloc][0] = vmax; P[ni][oloc][1] = vmin; P[ni][oloc][2] = vsum;
        }
    }
    __syncthreads();
    if (w >= 2 && quad == 0){
        #pragma unroll
        for (int ni = 0; ni < 5; ++ni){
            int oloc = olocb + ni*16;
            int o = nbase + oloc;
            if (o < NH_){
                float vmax = fmaxf(rmax[ni], P[ni][oloc][0]);
                float vmin = fminf(rmin[ni], P[ni][oloc][1]);
                float vsum = rsum[ni] + P[ni][oloc][2];
                long base = ((long)((s*3 + (WS-1))*3)) * (long)(B_*NH_) + (long)b*NH_ + o;
                apool[base]                  = fast_tanh(vmax);
                apool[base + (long)(B_*NH_)] = -fast_tanh(vmin);
                apool[base + 2L*(B_*NH_)]    = vsum / (float)Lo;
            }
        }
    }
}

// ------------------------------------------------- per-dim conv + pooling v2
__global__ __launch_bounds__(256) void k_pdim(const float* __restrict__ S,
    const float* __restrict__ pw1, const float* __restrict__ pb1,
    const float* __restrict__ pw2, const float* __restrict__ pb2,
    const float* __restrict__ pw3, const float* __restrict__ pb3,
    float* __restrict__ ppool){
    long tid = (long)blockIdx.x*256 + threadIdx.x;   // < 1,536,000
    int k = (int)(tid % 20);
    long r = tid / 20;
    int c = (int)(r % 300); r /= 300;
    int b = (int)(r % 128); int s = (int)(r / 128);
    const float* row = S + (long)c*N2_ + (long)s*N_ + b*64;
    int ck = c*20 + k;
    float w10 = pw1[ck];
    float w20 = pw2[ck*2], w21 = pw2[ck*2+1];
    float w30 = pw3[ck*3], w31 = pw3[ck*3+1], w32 = pw3[ck*3+2];
    float bb1 = pb1[ck], bb2 = pb2[ck], bb3 = pb3[ck];

    float x[64];
    const float4* rp = (const float4*)row;
    #pragma unroll
    for (int i = 0; i < 16; ++i){
        float4 v = rp[i];
        x[i*4+0]=v.x; x[i*4+1]=v.y; x[i*4+2]=v.z; x[i*4+3]=v.w;
    }

    float mx1=-1e30f, mn1=1e30f, mx2=-1e30f, mn2=1e30f, mx3=-1e30f, mn3=1e30f;
    #pragma unroll
    for (int t = 0; t < 64; ++t){
        float z1 = fmaf(w10, x[t], bb1);
        mx1 = fmaxf(mx1, z1); mn1 = fminf(mn1, z1);
    }
    #pragma unroll
    for (int t = 0; t < 63; ++t){
        float z2 = fmaf(w21, x[t+1], fmaf(w20, x[t], bb2));
        mx2 = fmaxf(mx2, z2); mn2 = fminf(mn2, z2);
    }
    #pragma unroll
    for (int t = 0; t < 62; ++t){
        float z3 = fmaf(w32, x[t+2], fmaf(w31, x[t+1], fmaf(w30, x[t], bb3)));
        mx3 = fmaxf(mx3, z3); mn3 = fminf(mn3, z3);
    }

    float outs[6] = { fast_tanh(mx1), -fast_tanh(mn1),
                      fast_tanh(mx2), -fast_tanh(mn2),
                      fast_tanh(mx3), -fast_tanh(mn3) };
    long stride_sw = 128L*6000L;
    long off = (long)b*6000 + (long)c*20 + k;
    #pragma unroll
    for (int wsi = 0; wsi < 3; ++wsi)
        #pragma unroll
        for (int pool = 0; pool < 2; ++pool){
            long slot = (long)((s*3+wsi)*2 + pool);
            ppool[slot*stride_sw + off] = outs[wsi*2+pool];
        }
}

// ------------------------------------------------- whole-sentence (inf) pools
__global__ void k_inf(const float* __restrict__ S, float* __restrict__ ainf){
    int sbx = blockIdx.x; int s = sbx >> 7, b = sbx & 127;
    int tid = threadIdx.x;
    long base = (long)s*N_ + b*64;
    float vmax = -1e30f, vnmax = -1e30f, vsum = 0.f;
    for (int idx = tid; idx < C_*64; idx += 256){
        int c = idx >> 6, l = idx & 63;
        float v = S[(long)c*N2_ + base + l];
        vmax = fmaxf(vmax, v);
        vnmax = fmaxf(vnmax, -v);
        vsum += v;
    }
    for (int m = 1; m < 64; m <<= 1){
        vmax  = fmaxf(vmax,  __shfl_xor(vmax, m, 64));
        vnmax = fmaxf(vnmax, __shfl_xor(vnmax, m, 64));
        vsum += __shfl_xor(vsum, m, 64);
    }
    __shared__ float red[3][4];
    int w = tid >> 6;
    if ((tid & 63) == 0){ red[0][w]=vmax; red[1][w]=vnmax; red[2][w]=vsum; }
    __syncthreads();
    if (tid == 0){
        float a = fmaxf(fmaxf(red[0][0],red[0][1]),fmaxf(red[0][2],red[0][3]));
        float nn= fmaxf(fmaxf(red[1][0],red[1][1]),fmaxf(red[1][2],red[1][3]));
        float su= red[2][0]+red[2][1]+red[2][2]+red[2][3];
        ainf[(s*3+0)*128 + b] = a;
        ainf[(s*3+1)*128 + b] = nn;
        ainf[(s*3+2)*128 + b] = su / (float)(C_*64);
    }
}

// ------------------------------------------------- finite-ws pair features
__global__ void k_pairs(const float* __restrict__ apool, float* __restrict__ feat){
    int b = blockIdx.x, p = blockIdx.y, q = blockIdx.z;
    int w1 = q / 3, w2 = q % 3;
    int lane = threadIdx.x;
    const float* x1 = apool + ((long)((0*3 + w1)*3 + p))*(long)(B_*NH_) + (long)b*NH_;
    const float* x2 = apool + ((long)((1*3 + w2)*3 + p))*(long)(B_*NH_) + (long)b*NH_;
    float dot=0, n1=0, n2=0, d2=0;
    long fb = (long)b*FSTRIDE_;
    long vbase = 24 + (long)p*2721 + (long)q*302;
    for (int i = lane; i < NH_; i += 64){
        float a = x1[i], bb = x2[i];
        dot = fmaf(a, bb, dot); n1 = fmaf(a, a, n1); n2 = fmaf(bb, bb, n2);
        float dd = a - bb + 1e-6f;
        d2 = fmaf(dd, dd, d2);
        feat[fb + vbase + 2 + i] = fabsf(a - bb);
    }
    for (int m = 1; m < 64; m <<= 1){
        dot += __shfl_xor(dot, m, 64);
        n1  += __shfl_xor(n1, m, 64);
        n2  += __shfl_xor(n2, m, 64);
        d2  += __shfl_xor(d2, m, 64);
    }
    if (lane == 0){
        float cosv = dot / fmaxf(sqrtf(n1)*sqrtf(n2), 1e-8f);
        float distv = sqrtf(d2);
        feat[fb + vbase + 0] = cosv;
        feat[fb + vbase + 1] = distv;
        if (w1 == w2){
            feat[fb + p*8 + w1*2 + 0] = cosv;
            feat[fb + p*8 + w1*2 + 1] = distv;
        }
    }
}

// ------------------------------------------------- inf features (scalar dims)
__global__ void k_infeat(const float* __restrict__ ainf, float* __restrict__ feat){
    int t = threadIdx.x;
    if (t >= 384) return;
    int b = t & 127, p = t >> 7;
    float x1 = ainf[(0*3+p)*128 + b];
    float x2 = ainf[(1*3+p)*128 + b];
    float cosv = (x1*x2) / fmaxf(fabsf(x1)*fabsf(x2), 1e-8f);
    float distv = fabsf(x1 - x2 + 1e-6f);
    long fb = (long)b*FSTRIDE_;
    feat[fb + p*8 + 6] = cosv;
    feat[fb + p*8 + 7] = distv;
    long vb = 24 + (long)p*2721 + 9L*302;
    feat[fb + vb + 0] = cosv;
    feat[fb + vb + 1] = distv;
    feat[fb + vb + 2] = fabsf(x1 - x2);
}

// ------------------------------------------------- per-dim pair features v2
// One 256-thread block per (b, pw). Stage both 6000-float rows coalesced from
// global, transpose to LDS [k][305]. Wave w reduces k = w, w+4, ... — identical
// lane->c map + shuffle order as v1 (bit-identical results).
__global__ __launch_bounds__(256) void k_pdimfeat(const float* __restrict__ ppool,
                                                  float* __restrict__ feat){
    __shared__ float X1[20*305];
    __shared__ float X2[20*305];
    int b = blockIdx.x, pw = blockIdx.y;
    int pool = pw / 3, wsi = pw % 3;
    int tid = threadIdx.x;
    long stride_sw = 128L*6000L;
    const float* x1 = ppool + (long)((0*3+wsi)*2+pool)*stride_sw + (long)b*6000;
    const float* x2 = ppool + (long)((1*3+wsi)*2+pool)*stride_sw + (long)b*6000;
    for (int idx = tid; idx < 6000; idx += 256){
        int c = idx / 20, k = idx - 20*c;      // element (c,k): original x[c*20+k]
        X1[k*305 + c] = x1[idx];
        X2[k*305 + c] = x2[idx];
    }
    __syncthreads();
    int w = tid >> 6, lane = tid & 63;
    for (int k = w; k < 20; k += 4){
        float dot=0, n1=0, n2=0, d2=0;
        long fb = (long)b*FSTRIDE_ + 8187 + (long)pw*6040 + (long)k*302;
        for (int c = lane; c < C_; c += 64){
            float a = X1[k*305 + c], bb = X2[k*305 + c];
            dot = fmaf(a, bb, dot); n1 = fmaf(a, a, n1); n2 = fmaf(bb, bb, n2);
            float dd = a - bb + 1e-6f;
            d2 = fmaf(dd, dd, d2);
            feat[fb + 2 + c] = fabsf(a - bb);
        }
        for (int m = 1; m < 64; m <<= 1){
            dot += __shfl_xor(dot, m, 64);
            n1  += __shfl_xor(n1, m, 64);
            n2  += __shfl_xor(n2, m, 64);
            d2  += __shfl_xor(d2, m, 64);
        }
        if (lane == 0){
            feat[fb + 0] = dot / fmaxf(sqrtf(n1)*sqrtf(n2), 1e-8f);
            feat[fb + 1] = sqrtf(d2);
        }
    }
}

// ------------------------------------------------- MLP layer 1: MFMA split-K v6
// C[128,150] = feat @ W1 via bf16 hi/lo split (3-term: hh + lh + hl), fp32 accum.
// A rows FSTRIDE_-padded (16B aligned) -> 2x float4 loads per step per lane;
// masked scalar path only on the final partial k-step.
__global__ __launch_bounds__(512) void k_mlp1(const float* __restrict__ feat,
        const float* __restrict__ W1, float* __restrict__ hpart){
    __shared__ __align__(16) unsigned short Bh[2][5120];   // 4 k-octets * 160 n * 8
    __shared__ __align__(16) unsigned short Bl[2][5120];
    int tid = threadIdx.x;
    int w = tid >> 6, lane = tid & 63, col = lane & 15, quad = lane >> 4;
    int z = blockIdx.x;
    int t0 = z * KCB_;
    int ns = KST_ - t0; if (ns > KCB_) ns = KCB_;
    long hbase = (long)z * (128*160);
    int mrow = w*16 + col;                       // wave's m-tile row for A-frag

    if (ns <= 0){
        #pragma unroll
        for (int ni = 0; ni < 10; ++ni)
            #pragma unroll
            for (int r = 0; r < 4; ++r)
                hpart[hbase + (long)(w*16 + quad*4 + r)*160 + ni*16 + col] = 0.0f;
        return;
    }

    // B staging assignment: 2560 (k-pair, n) cells, 5 per thread (constant per step)
    int k2a[5], na[5];
    #pragma unroll
    for (int i = 0; i < 5; ++i){
        int p = i*512 + tid;
        k2a[i] = p / 160; na[i] = p - 160*k2a[i];   // k2 in 0..15 (k = 2*k2), n in 0..159
    }

    const float* arow = feat + (long)mrow * FSTRIDE_;
    float af[8];                 // raw A dwords for current/next step
    float bf0[5], bf1[5];        // raw B pair values
    bf16x8 ah, al;               // current A frags
    f32x4 acc[10] = {};

#define LOADA(STEP) do { \
        int ks_ = t0 + (STEP); \
        int kb_ = ks_*32 + quad*8; \
        if (ks_ < 1388){ \
            float4 f0_ = *(const float4*)(arow + kb_); \
            float4 f1_ = *(const float4*)(arow + kb_ + 4); \
            af[0]=f0_.x; af[1]=f0_.y; af[2]=f0_.z; af[3]=f0_.w; \
            af[4]=f1_.x; af[5]=f1_.y; af[6]=f1_.z; af[7]=f1_.w; \
        } else { \
            _Pragma("unroll") \
            for (int j_ = 0; j_ < 8; ++j_){ \
                int k_ = kb_ + j_; \
                af[j_] = (k_ < NFEAT_) ? arow[k_] : 0.0f; \
            } \
        } } while(0)

#define LOADB(STEP) do { \
        int kb_ = (t0 + (STEP))*32; \
        _Pragma("unroll") \
        for (int i_ = 0; i_ < 5; ++i_){ \
            int k_ = kb_ + 2*k2a[i_]; int n_ = na[i_]; \
            bf0[i_] = (k_   < NFEAT_ && n_ < HID_) ? W1[(long)k_*HID_ + n_]     : 0.0f; \
            bf1[i_] = (k_+1 < NFEAT_ && n_ < HID_) ? W1[(long)(k_+1)*HID_ + n_] : 0.0f; \
        } } while(0)

#define CVTA() do { \
        _Pragma("unroll") \
        for (int j_ = 0; j_ < 8; ++j_){ \
            unsigned short h_ = f2bf(af[j_]); \
            unsigned short l_ = f2bf(af[j_] - bf2f(h_)); \
            ah[j_] = (short)h_; al[j_] = (short)l_; \
        } } while(0)

#define WRITEB(BUF) do { \
        _Pragma("unroll") \
        for (int i_ = 0; i_ < 5; ++i_){ \
            int k2_ = k2a[i_]; int n_ = na[i_]; \
            int q_ = k2_ >> 2, off_ = k2_ & 3; \
            unsigned short h0_ = f2bf(bf0[i_]); \
            unsigned short l0_ = f2bf(bf0[i_] - bf2f(h0_)); \
            unsigned short h1_ = f2bf(bf1[i_]); \
            unsigned short l1_ = f2bf(bf1[i_] - bf2f(h1_)); \
            int ui_ = (q_*160 + n_)*4 + off_; \
            ((unsigned*)Bh[BUF])[ui_] = (unsigned)h0_ | ((unsigned)h1_ << 16); \
            ((unsigned*)Bl[BUF])[ui_] = (unsigned)l0_ | ((unsigned)l1_ << 16); \
        } } while(0)

    // prologue: fetch step 0, stage B(0) into buf 0
    LOADB(0);
    LOADA(0);
    WRITEB(0);

    for (int t = 0; t < ns; ++t){
        __syncthreads();                       // B(t) LDS writes visible to all waves
        CVTA();                                // A(t) raw -> frags (waits its vmcnt)
        bool more = (t+1 < ns);
        if (more){ LOADA(t+1); LOADB(t+1); }   // issue next-step global loads early
        int bi = t & 1;
        #pragma unroll
        for (int ni = 0; ni < 10; ++ni){
            bf16x8 bh = *(const bf16x8*)&Bh[bi][(quad*160 + ni*16 + col)*8];
            bf16x8 bl = *(const bf16x8*)&Bl[bi][(quad*160 + ni*16 + col)*8];
            acc[ni] = __builtin_amdgcn_mfma_f32_16x16x32_bf16(ah, bh, acc[ni], 0,0,0);
            acc[ni] = __builtin_amdgcn_mfma_f32_16x16x32_bf16(al, bh, acc[ni], 0,0,0);
            acc[ni] = __builtin_amdgcn_mfma_f32_16x16x32_bf16(ah, bl, acc[ni], 0,0,0);
        }
        if (more) WRITEB((t+1)&1);             // waits B(t+1) vmcnt; other buffer
    }

#undef LOADA
#undef LOADB
#undef CVTA
#undef WRITEB

    #pragma unroll
    for (int ni = 0; ni < 10; ++ni)
        #pragma unroll
        for (int r = 0; r < 4; ++r)
            hpart[hbase + (long)(w*16 + quad*4 + r)*160 + ni*16 + col] = acc[ni][r];
}

// ------------------------------------------------- reduce split-K partials v2
// grid (75, 4): y-chunk sums 64 z's -> 300 blocks. k_final sums the 4 slices.
__global__ void k_red(const float* __restrict__ hpart, float* __restrict__ hpre4){
    int t = blockIdx.x*256 + threadIdx.x;
    if (t >= 128*HID_) return;
    int y = blockIdx.y;
    int b = t / HID_, n = t % HID_;
    float s = 0.0f;
    int z0 = y*64;
    for (int z = z0; z < z0+64; ++z)
        s += hpart[(long)z*(128*160) + (long)b*160 + n];
    hpre4[(long)y*(128*HID_) + t] = s;
}

// ------------------------------------------------- tanh + layer2 + log_softmax
__global__ void k_final(const float* __restrict__ hpre4, const float* __restrict__ b1,
        const float* __restrict__ W2, const float* __restrict__ b2,
        float* __restrict__ out){
    int b = threadIdx.x;
    if (b >= 128) return;
    float z0 = b2[0], z1 = b2[1];
    for (int n = 0; n < HID_; ++n){
        int idx = b*HID_ + n;
        float hp = hpre4[idx] + hpre4[19200 + idx] + hpre4[38400 + idx] + hpre4[57600 + idx];
        float hv = fast_tanh(hp + b1[n]);
        z0 = fmaf(hv, W2[n*2+0], z0);
        z1 = fmaf(hv, W2[n*2+1], z1);
    }
    float m = fmaxf(z0, z1);
    float lse = m + logf(expf(z0-m) + expf(z1-m));
    out[b*2+0] = z0 - lse;
    out[b*2+1] = z1 - lse;
}

extern "C" void kernel_launch(void* const* d_in, const int* in_sizes, int n_in,
                              void* d_out, int out_size, void* d_ws, size_t ws_size,
                              hipStream_t stream){
    const int*   sa  = (const int*)d_in[0];
    const int*   sb  = (const int*)d_in[1];
    const float* emb = (const float*)d_in[2];
    const float* hw1 = (const float*)d_in[3];
    const float* hb1 = (const float*)d_in[4];
    const float* pw1 = (const float*)d_in[5];
    const float* pb1 = (const float*)d_in[6];
    const float* hw2 = (const float*)d_in[7];
    const float* hb2 = (const float*)d_in[8];
    const float* pw2 = (const float*)d_in[9];
    const float* pb2 = (const float*)d_in[10];
    const float* hw3 = (const float*)d_in[11];
    const float* hb3 = (const float*)d_in[12];
    const float* pw3 = (const float*)d_in[13];
    const float* pb3 = (const float*)d_in[14];
    const float* W1  = (const float*)d_in[15];
    const float* b1  = (const float*)d_in[16];
    const float* W2  = (const float*)d_in[17];
    const float* b2  = (const float*)d_in[18];
    float* out = (float*)d_out;

    float* ws    = (float*)d_ws;
    float* S     = ws;                       // 300*16384      = 4,915,200
    float* APOOL = S + 4915200;              // 2*3*3*128*300  =   691,200
    float* AINF  = APOOL + 691200;           // 2*3*128        =       768
    float* PPOOL = AINF + 768;               // 2*3*2*128*6000 = 9,216,000
    float* FEAT  = PPOOL + 9216000;          // 128*44428      = 5,686,784 (padded rows)
    float* HPRE  = FEAT + 5686784;           // 4*128*150      =    76,800
    // time-multiplexed overlays:
    //  - SbfT (16448*320 bf16 = 2,631,680 floats) + Wbf overlay PPOOL until hconv7
    //    finishes (k_pdim then overwrites)
    //  - HPART (256*128*160 = 5,242,880 floats) overlays S..AINF (dead by mlp1)
    unsigned short* SBFT = (unsigned short*)PPOOL;
    unsigned short* WBF  = (unsigned short*)(PPOOL + 2631680);
    float* HPART = ws;

    k_embed<<<dim3(64, 5), 256, 0, stream>>>(sa, sb, emb, S);
    k_embedT<<<257, 256, 0, stream>>>(sa, sb, emb, SBFT);
    k_wprep<<<2400, 256, 0, stream>>>(hw1, hw2, hw3, WBF);
    k_hconv7<<<1536, 256, 0, stream>>>(SBFT, WBF, hb1, hb2, hb3, APOOL);
    k_pdim<<<6000, 256, 0, stream>>>(S, pw1,pb1, pw2,pb2, pw3,pb3, PPOOL);
    k_inf<<<256, 256, 0, stream>>>(S, AINF);
    k_pairs<<<dim3(128,3,9), 64, 0, stream>>>(APOOL, FEAT);
    k_infeat<<<1, 384, 0, stream>>>(AINF, FEAT);
    k_pdimfeat<<<dim3(128, 6), 256, 0, stream>>>(PPOOL, FEAT);
    k_mlp1<<<dim3(ZB_), 512, 0, stream>>>(FEAT, W1, HPART);
    k_red<<<dim3(75, 4), 256, 0, stream>>>(HPART, HPRE);
    k_final<<<1, 128, 0, stream>>>(HPRE, b1, W2, b2, out);
}